// Round 9
// baseline (546.745 us; speedup 1.0000x reference)
//
#include <hip/hip_runtime.h>
#include <stdint.h>

// ---- problem constants ----
#define B_   4
#define L_   2048
#define DM   1024
#define DIN  2048
#define NH   32
#define HD   64
#define DSTATE 64
#define DCONV  7
#define CONV_DIM 2176            // DIN + 2*DSTATE
#define DPROJ 4288               // 2*DIN + 2*DSTATE + 2*NH
#define NPAD 4352                // DPROJ padded to 128
#define BL   8192                // B_*L_
#define EPS  1e-5f
#define QC   128                 // scan chunk length
#define NCH  16                  // chunks per sequence

typedef unsigned short u16;
typedef unsigned int   u32;
typedef __bf16 bf16x8 __attribute__((ext_vector_type(8)));
typedef float  f32x4  __attribute__((ext_vector_type(4)));

__device__ __forceinline__ float b2f(u32 b) { return __uint_as_float(b << 16); }
__device__ __forceinline__ u16 f2b(float f) {
    u32 u = __float_as_uint(f);
    u32 r = (u + 0x7fffu + ((u >> 16) & 1u)) >> 16;
    return (u16)r;
}
__device__ __forceinline__ void unpack8(uint4 v, float* f) {
    f[0] = b2f(v.x & 0xffffu); f[1] = b2f(v.x >> 16);
    f[2] = b2f(v.y & 0xffffu); f[3] = b2f(v.y >> 16);
    f[4] = b2f(v.z & 0xffffu); f[5] = b2f(v.z >> 16);
    f[6] = b2f(v.w & 0xffffu); f[7] = b2f(v.w >> 16);
}
__device__ __forceinline__ uint4 pack8(const float* f) {
    uint4 v;
    v.x = (u32)f2b(f[0]) | ((u32)f2b(f[1]) << 16);
    v.y = (u32)f2b(f[2]) | ((u32)f2b(f[3]) << 16);
    v.z = (u32)f2b(f[4]) | ((u32)f2b(f[5]) << 16);
    v.w = (u32)f2b(f[6]) | ((u32)f2b(f[7]) << 16);
    return v;
}
// skewed LDS index for transposed tiles: row-stride 136 u16 + 8-u16 skew per 8 rows.
__device__ __forceinline__ int xts(int p, int s) { return p * 136 + ((p >> 3) << 3) + s; }
// async global->LDS, 16B per lane; lds base must be wave-uniform (HW adds lane*16)
__device__ __forceinline__ void gload_lds16(const u16* g, u16* l) {
    __builtin_amdgcn_global_load_lds((const __attribute__((address_space(1))) void*)g,
                                     (__attribute__((address_space(3))) void*)l, 16, 0, 0);
}

// ---------- prep A: layernorm + W_in/W_out cvt (targets disjoint from u_bf alias region) ----------
// MUST run before GEMM1. block ranges: [0,8192) ln ; [8192,12544) cvt_win ; [12544,14592) cvt_wout
#define GP_LN    8192
#define GP_WIN   4352
#define GP_WOUT  2048
#define GP_FCD   64
#define GP_DZ    1024
__global__ __launch_bounds__(256) void k_prep_a(const float* __restrict__ x, const float* __restrict__ g,
                                                const float* __restrict__ be, u16* __restrict__ u,
                                                const float* __restrict__ Wi, u16* __restrict__ wib,
                                                const float* __restrict__ Wo, u16* __restrict__ wob) {
    int bb = blockIdx.x, tid = threadIdx.x;
    if (bb < GP_LN) {
        int row = bb;
        const float4* xr = (const float4*)(x + (size_t)row * DM);
        float4 v = xr[tid];
        float s1 = v.x + v.y + v.z + v.w;
        float s2 = v.x * v.x + v.y * v.y + v.z * v.z + v.w * v.w;
        for (int o = 32; o; o >>= 1) { s1 += __shfl_down(s1, o); s2 += __shfl_down(s2, o); }
        __shared__ float ls1[4], ls2[4];
        int w = tid >> 6;
        if ((tid & 63) == 0) { ls1[w] = s1; ls2[w] = s2; }
        __syncthreads();
        float t1 = ls1[0] + ls1[1] + ls1[2] + ls1[3];
        float t2 = ls2[0] + ls2[1] + ls2[2] + ls2[3];
        float mu = t1 * (1.f / DM);
        float var = t2 * (1.f / DM) - mu * mu;
        float rs = rsqrtf(var + EPS);
        float4 gv = ((const float4*)g)[tid];
        float4 bv = ((const float4*)be)[tid];
        float o0 = (v.x - mu) * rs * gv.x + bv.x;
        float o1 = (v.y - mu) * rs * gv.y + bv.y;
        float o2 = (v.z - mu) * rs * gv.z + bv.z;
        float o3 = (v.w - mu) * rs * gv.w + bv.w;
        uint2 p;
        p.x = (u32)f2b(o0) | ((u32)f2b(o1) << 16);
        p.y = (u32)f2b(o2) | ((u32)f2b(o3) << 16);
        ((uint2*)(u + (size_t)row * DM))[tid] = p;
    } else if (bb < GP_LN + GP_WIN) {
        int idx4 = ((bb - GP_LN) * 256 + tid) * 4;      // over NPAD*DM
        int n = idx4 >> 10, col = idx4 & 1023;
        uint2 p = {0u, 0u};
        if (n < DPROJ) {
            float4 v = *(const float4*)(Wi + (size_t)n * DM + col);
            p.x = (u32)f2b(v.x) | ((u32)f2b(v.y) << 16);
            p.y = (u32)f2b(v.z) | ((u32)f2b(v.w) << 16);
        }
        *(uint2*)(wib + idx4) = p;
    } else {
        int idx4 = ((bb - GP_LN - GP_WIN) * 256 + tid) * 4;   // over DM*DIN
        float4 v = *(const float4*)(Wo + idx4);
        uint2 p;
        p.x = (u32)f2b(v.x) | ((u32)f2b(v.y) << 16);
        p.y = (u32)f2b(v.z) | ((u32)f2b(v.w) << 16);
        *(uint2*)(wob + idx4) = p;
    }
}

// ---------- prep B: fc_D cvt + Dd seed. WRITES INTO DEAD u_bf REGION -> must run AFTER GEMM1 ----------
__global__ __launch_bounds__(256) void k_prep_b(const float* __restrict__ Wf, u16* __restrict__ fcb,
                                                const float* __restrict__ Dv, float* __restrict__ Dd) {
    int bb = blockIdx.x, tid = threadIdx.x;
    if (bb < GP_FCD) {
        int idx4 = (bb * 256 + tid) * 4;                // over NH*DIN
        float4 v = *(const float4*)(Wf + idx4);
        uint2 p;
        p.x = (u32)f2b(v.x) | ((u32)f2b(v.y) << 16);
        p.y = (u32)f2b(v.z) | ((u32)f2b(v.w) << 16);
        *(uint2*)(fcb + idx4) = p;
    } else {
        int idx = (bb - GP_FCD) * 256 + tid;            // over BL*32
        Dd[idx] = Dv[idx & 31];
    }
}

// ---------- bf16 MFMA GEMM, C[m,n] = sum_k A[m,k]*B[n,k]  (B^T layout) ----------
// 128x128 tile, 2-barrier K-loop, global_load_lds width=16 staging (proven m97
// structure). 256^2 deep-pipeline variants tried in rounds 1-4 all regressed
// (103-120 us, MfmaUtil <30%) -- do not revisit without new evidence.
// Cross-acquisition noise ~+/-10% (95.4 us r0/r6 vs ~110-112 us r5/r7).
__global__ __launch_bounds__(256) void k_gemm_bt(const u16* __restrict__ A, const u16* __restrict__ Bw,
                                                 int M, int N, int K, int out_bf16,
                                                 u16* __restrict__ obf, int ldo,
                                                 float* __restrict__ ofp, const float* __restrict__ res) {
    __shared__ __align__(16) u16 As[128 * 64];
    __shared__ __align__(16) u16 Bs[128 * 64];
    int tid = threadIdx.x;
    int m0 = blockIdx.y * 128, n0 = blockIdx.x * 128;
    int w = tid >> 6, lane = tid & 63;
    int wm = (w >> 1) * 64, wn = (w & 1) * 64;
    int lr = lane & 15, lq = lane >> 4;

    f32x4 acc[4][4];
    #pragma unroll
    for (int i = 0; i < 4; i++)
        #pragma unroll
        for (int j = 0; j < 4; j++) acc[i][j] = (f32x4){0.f, 0.f, 0.f, 0.f};

    for (int kt = 0; kt < K; kt += 64) {
        #pragma unroll
        for (int it = 0; it < 4; it++) {
            int s_idx = it * 256 + tid;
            int row = s_idx >> 3;
            int kcg = (s_idx & 7) ^ (row & 7);            // swizzled source chunk
            u16* lbase_a = &As[(it * 256 + w * 64) * 8];  // wave-uniform
            u16* lbase_b = &Bs[(it * 256 + w * 64) * 8];
            gload_lds16(A + (size_t)(m0 + row) * K + kt + kcg * 8, lbase_a);
            gload_lds16(Bw + (size_t)(n0 + row) * K + kt + kcg * 8, lbase_b);
        }
        __syncthreads();
        #pragma unroll
        for (int kk = 0; kk < 2; kk++) {
            bf16x8 af[4], bfr[4];
            #pragma unroll
            for (int i = 0; i < 4; i++) {
                int row = wm + 16 * i + lr;
                af[i] = *(const bf16x8*)&As[row * 64 + (((kk * 4 + lq)) ^ (row & 7)) * 8];
            }
            #pragma unroll
            for (int j = 0; j < 4; j++) {
                int row = wn + 16 * j + lr;
                bfr[j] = *(const bf16x8*)&Bs[row * 64 + (((kk * 4 + lq)) ^ (row & 7)) * 8];
            }
            #pragma unroll
            for (int i = 0; i < 4; i++)
                #pragma unroll
                for (int j = 0; j < 4; j++)
                    acc[i][j] = __builtin_amdgcn_mfma_f32_16x16x32_bf16(af[i], bfr[j], acc[i][j], 0, 0, 0);
        }
        __syncthreads();
    }
    #pragma unroll
    for (int i = 0; i < 4; i++) {
        #pragma unroll
        for (int j = 0; j < 4; j++) {
            #pragma unroll
            for (int rr = 0; rr < 4; rr++) {
                int m = m0 + wm + 16 * i + lq * 4 + rr;
                int n = n0 + wn + 16 * j + lr;
                float v = acc[i][j][rr];
                if (out_bf16) obf[(size_t)m * ldo + n] = f2b(v);
                else          ofp[(size_t)m * ldo + n] = v + res[(size_t)m * ldo + n];
            }
        }
    }
}

// ---------- D-projection GEMM, split-K x8: Dd[m][h] += partial dot(xs[m,:], fc_D_w[h,:]) ----------
__global__ __launch_bounds__(256) void k_dproj(const u16* __restrict__ xs, const u16* __restrict__ fcb,
                                               float* __restrict__ Dd) {
    __shared__ __align__(16) u16 As[32 * 72];
    __shared__ __align__(16) u16 Bs[32 * 72];
    int tid = threadIdx.x;
    int m0 = blockIdx.x * 32;
    int k0 = blockIdx.y * 256;                          // 8 K-slices of 256
    int w = tid >> 6, lane = tid & 63, lr = lane & 15, lq = lane >> 4;
    int mt = (w & 1) * 16, nt = (w >> 1) * 16;
    int r = tid >> 3, kc = tid & 7;
    f32x4 acc = (f32x4){0.f, 0.f, 0.f, 0.f};
    for (int kt = k0; kt < k0 + 256; kt += 64) {
        *(uint4*)&As[r * 72 + kc * 8] = *(const uint4*)(xs + (size_t)(m0 + r) * DIN + kt + kc * 8);
        *(uint4*)&Bs[r * 72 + kc * 8] = *(const uint4*)(fcb + (size_t)r * DIN + kt + kc * 8);
        __syncthreads();
        #pragma unroll
        for (int ks = 0; ks < 2; ks++) {
            bf16x8 a = *(const bf16x8*)&As[(mt + lr) * 72 + ks * 32 + lq * 8];
            bf16x8 b = *(const bf16x8*)&Bs[(nt + lr) * 72 + ks * 32 + lq * 8];
            acc = __builtin_amdgcn_mfma_f32_16x16x32_bf16(a, b, acc, 0, 0, 0);
        }
        __syncthreads();
    }
    #pragma unroll
    for (int rr = 0; rr < 4; rr++) {
        int m = m0 + mt + lq * 4 + rr;
        int n = nt + lr;
        atomicAdd(&Dd[(size_t)m * 32 + n], acc[rr]);
    }
}

// ---------- depthwise conv7 (same-pad) + bias + SiLU, split xs / BC(bf16) ----------
__global__ __launch_bounds__(256) void k_conv(const u16* __restrict__ zx, const float* __restrict__ cw,
                                              const float* __restrict__ cb, u16* __restrict__ xs,
                                              u16* __restrict__ BCb) {
    __shared__ u16 sh[262 * 64];
    int c0 = blockIdx.x * 64, t0 = blockIdx.y * 256, b = blockIdx.z;
    int tid = threadIdx.x;
    int c = tid & 63, tg = tid >> 6;
    for (int it = 0; it < 66; it++) {
        int r = it * 4 + tg;
        if (r < 262) {
            int t = t0 + r - 3;
            u16 v = 0;
            if (t >= 0 && t < L_) v = zx[(size_t)(b * L_ + t) * NPAD + DIN + c0 + c];
            sh[r * 64 + c] = v;
        }
    }
    float wgt[7];
    #pragma unroll
    for (int k = 0; k < 7; k++) wgt[k] = cw[(c0 + c) * 7 + k];
    float bias = cb[c0 + c];
    __syncthreads();
    int cg = c0 + c;
    for (int tt = 0; tt < 64; tt++) {
        int tl = tt * 4 + tg;
        float a = bias;
        #pragma unroll
        for (int k = 0; k < 7; k++) a += b2f(sh[(tl + k) * 64 + c]) * wgt[k];
        float v = a / (1.f + __expf(-a));   // silu
        size_t row = (size_t)b * L_ + (t0 + tl);
        if (cg < DIN) xs[row * DIN + cg] = f2b(v);
        else          BCb[row * 128 + (cg - DIN)] = f2b(v);   // B at [0,64), C at [64,128), bf16
    }
}

// ======================================================================
// Chunked SSD scan (intra-chunk + chunk-state + inline dt): block = (dir,b,h,chunk).
// R5: outputs staged through dead LDS, coalesced uint4 stores.
// R7: Y and S_c MFMA groups merged before a single barrier (tail 4 -> 2 barriers).
// ======================================================================
__global__ __launch_bounds__(256) void k_chunk(const u16* __restrict__ xs, const u16* __restrict__ BCb,
                                               const u16* __restrict__ zx, const float* __restrict__ dt_bias,
                                               const float* __restrict__ A_log, u16* __restrict__ y0,
                                               u16* __restrict__ y1, float* __restrict__ wout,
                                               float* __restrict__ decay, u16* __restrict__ scb) {
    __shared__ __align__(16) u16 ab[18432];      // Cs [0,9216) stride 72, Bs [9216,18432); S overlays (skewed 136); y-stage overlays [t][72]
    __shared__ __align__(16) u16 XT[8768];       // X^T [p][s] skewed
    __shared__ __align__(16) u16 BT[8768];       // B^T [n][s] skewed; scb-stage overlays [p][72]
    __shared__ __align__(16) float dts_s[128];
    __shared__ __align__(16) float lda_s[128];
    __shared__ __align__(16) float wend[128];
    __shared__ __align__(16) double cumd[128];

    const int blk = blockIdx.x;
    const int c = blk & 15, dbh = blk >> 4;
    const int h = dbh & 31, b = (dbh >> 5) & 3, dir = dbh >> 7;
    const int tid = threadIdx.x, w = tid >> 6, lane = tid & 63, lr = lane & 15, lq = lane >> 4;
    const int s0 = c * QC;
    u16* yo = dir ? y1 : y0;

    if (tid < 128) {   // inline dt2 / log-dA
        int s = s0 + tid;
        int t = dir ? (L_ - 1 - s) : s;
        float draw = b2f(zx[(size_t)(b * L_ + t) * NPAD + (DIN + CONV_DIM) + dir * 32 + h]);
        float xb = draw + dt_bias[h];
        float dt2 = (xb > 20.f) ? xb : log1pf(__expf(xb));
        dts_s[tid] = dt2;
        lda_s[tid] = -__expf(A_log[h]) * dt2;
    }
    {   // stage Cs, Bs (bf16 row-major), BT, XT (transposed, skewed)
        int sl0 = tid >> 3, ng = (tid & 7) * 8;
        #pragma unroll
        for (int it = 0; it < 4; it++) {
            int sl = sl0 + it * 32;
            int s = s0 + sl;
            int t = dir ? (L_ - 1 - s) : s;
            size_t row = (size_t)b * L_ + t;
            const u16* bcr = BCb + row * 128;
            uint4 cv = *(const uint4*)(bcr + 64 + ng);
            *(uint4*)&ab[sl * 72 + ng] = cv;
            uint4 pb = *(const uint4*)(bcr + ng);
            *(uint4*)&ab[9216 + sl * 72 + ng] = pb;
            u16 bh[8] = {(u16)(pb.x & 0xffffu), (u16)(pb.x >> 16), (u16)(pb.y & 0xffffu), (u16)(pb.y >> 16),
                         (u16)(pb.z & 0xffffu), (u16)(pb.z >> 16), (u16)(pb.w & 0xffffu), (u16)(pb.w >> 16)};
            #pragma unroll
            for (int i = 0; i < 8; i++) BT[(ng + i) * 136 + ng + sl] = bh[i];   // skew = ng
            uint4 xv = *(const uint4*)(xs + row * DIN + h * 64 + ng);
            u16 xh[8] = {(u16)(xv.x & 0xffffu), (u16)(xv.x >> 16), (u16)(xv.y & 0xffffu), (u16)(xv.y >> 16),
                         (u16)(xv.z & 0xffffu), (u16)(xv.z >> 16), (u16)(xv.w & 0xffffu), (u16)(xv.w >> 16)};
            #pragma unroll
            for (int i = 0; i < 8; i++) XT[(ng + i) * 136 + ng + sl] = xh[i];   // skew = ng
        }
    }
    __syncthreads();
    if (w == 0) {   // double-precision inclusive prefix of log-dA (wave 0)
        double v0 = (double)lda_s[lane];
        double v1 = (double)lda_s[64 + lane];
        #pragma unroll
        for (int o = 1; o < 64; o <<= 1) {
            double t0 = __shfl_up(v0, o);
            double t1 = __shfl_up(v1, o);
            if (lane >= o) { v0 += t0; v1 += t1; }
        }
        double tot0 = __shfl(v0, 63);
        cumd[lane] = v0;
        cumd[64 + lane] = tot0 + v1;
    }
    // G = C * B^T  (wave w owns t-rows [w*32, w*32+32))
    bf16x8 af[2][2];
    #pragma unroll
    for (int ti = 0; ti < 2; ti++)
        #pragma unroll
        for (int ks = 0; ks < 2; ks++)
            af[ti][ks] = *(const bf16x8*)&ab[(w * 32 + ti * 16 + lr) * 72 + ks * 32 + lq * 8];
    f32x4 accg[2][8];
    #pragma unroll
    for (int ti = 0; ti < 2; ti++)
        #pragma unroll
        for (int si = 0; si < 8; si++) accg[ti][si] = (f32x4){0.f, 0.f, 0.f, 0.f};
    #pragma unroll
    for (int si = 0; si < 8; si++)
        #pragma unroll
        for (int ks = 0; ks < 2; ks++) {
            bf16x8 bf = *(const bf16x8*)&ab[9216 + (si * 16 + lr) * 72 + ks * 32 + lq * 8];
            accg[0][si] = __builtin_amdgcn_mfma_f32_16x16x32_bf16(af[0][ks], bf, accg[0][si], 0, 0, 0);
            accg[1][si] = __builtin_amdgcn_mfma_f32_16x16x32_bf16(af[1][ks], bf, accg[1][si], 0, 0, 0);
        }
    __syncthreads();   // all G frag reads done; cumd ready
    // wend[s] = exp(cum[127]-cum[s])*dt[s]  (for chunk-state); visible after next barrier
    if (tid < 128) wend[tid] = __expf((float)(cumd[127] - cumd[tid])) * dts_s[tid];
    // S = M .* G  -> overlay into ab (skewed stride 136)
    {
        double cumt_d[8];
        #pragma unroll
        for (int ti = 0; ti < 2; ti++)
            #pragma unroll
            for (int r = 0; r < 4; r++) cumt_d[ti * 4 + r] = cumd[w * 32 + ti * 16 + lq * 4 + r];
        double cums_d[8]; float dts_l[8];
        #pragma unroll
        for (int si = 0; si < 8; si++) { cums_d[si] = cumd[si * 16 + lr]; dts_l[si] = dts_s[si * 16 + lr]; }
        #pragma unroll
        for (int ti = 0; ti < 2; ti++)
            #pragma unroll
            for (int si = 0; si < 8; si++)
                #pragma unroll
                for (int r = 0; r < 4; r++) {
                    int t_l = w * 32 + ti * 16 + lq * 4 + r;
                    int s_l = si * 16 + lr;
                    float v = 0.f;
                    if (s_l <= t_l)
                        v = __expf((float)(cumt_d[ti * 4 + r] - cums_d[si])) * dts_l[si] * accg[ti][si][r];
                    ab[xts(t_l, s_l)] = f2b(v);
                }
    }
    __syncthreads();
    // Y_intra = S * X^T
    f32x4 acc[2][4];
    #pragma unroll
    for (int ti = 0; ti < 2; ti++)
        #pragma unroll
        for (int pj = 0; pj < 4; pj++) acc[ti][pj] = (f32x4){0.f, 0.f, 0.f, 0.f};
    #pragma unroll
    for (int ks = 0; ks < 4; ks++) {
        bf16x8 a0 = *(const bf16x8*)&ab[xts(w * 32 + lr, ks * 32 + lq * 8)];
        bf16x8 a1 = *(const bf16x8*)&ab[xts(w * 32 + 16 + lr, ks * 32 + lq * 8)];
        #pragma unroll
        for (int pj = 0; pj < 4; pj++) {
            bf16x8 bf = *(const bf16x8*)&XT[xts(pj * 16 + lr, ks * 32 + lq * 8)];
            acc[0][pj] = __builtin_amdgcn_mfma_f32_16x16x32_bf16(a0, bf, acc[0][pj], 0, 0, 0);
            acc[1][pj] = __builtin_amdgcn_mfma_f32_16x16x32_bf16(a1, bf, acc[1][pj], 0, 0, 0);
        }
    }
    // chunk state S_c[p][n] = sum_s wend[s]*x[s][p]*B[s][n]  (merged: reads stable XT/BT/wend)
    f32x4 accs[4];
    #pragma unroll
    for (int nj = 0; nj < 4; nj++) accs[nj] = (f32x4){0.f, 0.f, 0.f, 0.f};
    #pragma unroll
    for (int ks = 0; ks < 4; ks++) {
        uint4 xv = *(const uint4*)&XT[xts(w * 16 + lr, ks * 32 + lq * 8)];
        float xf[8]; unpack8(xv, xf);
        float4 w0 = *(const float4*)&wend[ks * 32 + lq * 8];
        float4 w1 = *(const float4*)&wend[ks * 32 + lq * 8 + 4];
        float fs[8] = {xf[0]*w0.x, xf[1]*w0.y, xf[2]*w0.z, xf[3]*w0.w,
                       xf[4]*w1.x, xf[5]*w1.y, xf[6]*w1.z, xf[7]*w1.w};
        bf16x8 a = __builtin_bit_cast(bf16x8, pack8(fs));
        #pragma unroll
        for (int nj = 0; nj < 4; nj++) {
            bf16x8 bb = *(const bf16x8*)&BT[xts(nj * 16 + lr, ks * 32 + lq * 8)];
            accs[nj] = __builtin_amdgcn_mfma_f32_16x16x32_bf16(a, bb, accs[nj], 0, 0, 0);
        }
    }
    // ---- single barrier: all LDS reads (S/XT/BT) complete; stage both outputs ----
    __syncthreads();
    #pragma unroll
    for (int ti = 0; ti < 2; ti++)
        #pragma unroll
        for (int pj = 0; pj < 4; pj++)
            #pragma unroll
            for (int r = 0; r < 4; r++) {
                int t_l = w * 32 + ti * 16 + lq * 4 + r;
                ab[t_l * 72 + pj * 16 + lr] = f2b(acc[ti][pj][r]);   // Y: [t][p] stride 72
            }
    #pragma unroll
    for (int nj = 0; nj < 4; nj++)
        #pragma unroll
        for (int r = 0; r < 4; r++) {
            int p = w * 16 + lq * 4 + r, n = nj * 16 + lr;
            BT[p * 72 + n] = f2b(accs[nj][r]);                       // S_c: [p][n] stride 72
        }
    __syncthreads();
    // ---- coalesced stores ----
    #pragma unroll
    for (int k2 = 0; k2 < 4; k2++) {
        int c2 = k2 * 256 + tid;
        int t_l = c2 >> 3, p0 = (c2 & 7) * 8;
        int s = s0 + t_l;
        int t = dir ? (L_ - 1 - s) : s;
        *(uint4*)(yo + ((size_t)b * L_ + t) * DIN + h * 64 + p0) = *(const uint4*)&ab[t_l * 72 + p0];
    }
    #pragma unroll
    for (int k2 = 0; k2 < 2; k2++) {
        int c2 = k2 * 256 + tid;
        int p = c2 >> 3, n0 = (c2 & 7) * 8;
        *(uint4*)(scb + (size_t)blk * 4096 + p * 64 + n0) = *(const uint4*)&BT[p * 72 + n0];
    }
    if (tid < 128) wout[dbh * 2048 + s0 + tid] = __expf((float)cumd[tid]);
    if (tid == 0)  decay[blk] = __expf((float)cumd[127]);
}

// ======================================================================
// Merged h-scan + inter-chunk. block = (dbh, 16-row p-slice); 1024 blocks.
// h[16p][64n] slice in f32 registers; 16 chunks serial: publish bf16(h)->LDS,
// stage Csc, MFMA y' = Csc x h, h = decay*h + S_c (regs), coalesced y-RMW.
// Arithmetic identical to old hscan+inter.
// ======================================================================
__global__ __launch_bounds__(256) void k_hinter(const u16* __restrict__ BCb, const float* __restrict__ wout,
                                                const float* __restrict__ decay, const u16* __restrict__ scb,
                                                u16* __restrict__ y0, u16* __restrict__ y1) {
    __shared__ __align__(16) u16 Csc[128 * 72];          // wout[s]*C[s][n]
    __shared__ __align__(16) u16 hs[16 * 72];            // bf16(h) rows (local p)
    __shared__ __align__(16) float ybuf[128 * 20];       // f32 y' stage [t][p]
    const int bid = blockIdx.x;
    const int dbh = bid >> 2, ps = bid & 3;
    const int p0 = ps * 16;
    const int h = dbh & 31, b = (dbh >> 5) & 3, dir = dbh >> 7;
    const int tid = threadIdx.x, w = tid >> 6, lane = tid & 63, lr = lane & 15, lq = lane >> 4;
    u16* yo = dir ? y1 : y0;

    const int hp = tid >> 4;            // local p row owned (0..15)
    const int hn = (tid & 15) * 4;      // n offset (4 f32 per thread)
    float hreg[4] = {0.f, 0.f, 0.f, 0.f};

    const int sl0 = tid >> 3, ng = (tid & 7) * 8;
    const int rmw_t = tid >> 1, rmw_p = (tid & 1) * 8;

    for (int c = 0; c < NCH; c++) {
        // (1) publish bf16(h) entering chunk c (prior reads fenced by loop-end barrier)
        {
            uint2 pk;
            pk.x = (u32)f2b(hreg[0]) | ((u32)f2b(hreg[1]) << 16);
            pk.y = (u32)f2b(hreg[2]) | ((u32)f2b(hreg[3]) << 16);
            *(uint2*)&hs[hp * 72 + hn] = pk;
        }
        // (2) stage Csc = wout[s] * C[s][:]
        #pragma unroll
        for (int it = 0; it < 4; it++) {
            int sl = sl0 + it * 32;
            int s = c * QC + sl;
            int t = dir ? (L_ - 1 - s) : s;
            const u16* bcr = BCb + ((size_t)b * L_ + t) * 128 + 64 + ng;
            float sc = wout[dbh * 2048 + s];
            uint4 cv = *(const uint4*)bcr;
            float cf[8]; unpack8(cv, cf);
            float f[8] = {cf[0]*sc, cf[1]*sc, cf[2]*sc, cf[3]*sc, cf[4]*sc, cf[5]*sc, cf[6]*sc, cf[7]*sc};
            *(uint4*)&Csc[sl * 72 + ng] = pack8(f);
        }
        __syncthreads();
        // (3) MFMA: D[128 t][16 p]; wave w owns t-rows [w*32, w*32+32)
        f32x4 acc[2];
        acc[0] = (f32x4){0.f, 0.f, 0.f, 0.f};
        acc[1] = (f32x4){0.f, 0.f, 0.f, 0.f};
        #pragma unroll
        for (int ks = 0; ks < 2; ks++) {
            bf16x8 a0 = *(const bf16x8*)&Csc[(w * 32 + lr) * 72 + ks * 32 + lq * 8];
            bf16x8 a1 = *(const bf16x8*)&Csc[(w * 32 + 16 + lr) * 72 + ks * 32 + lq * 8];
            bf16x8 bb = *(const bf16x8*)&hs[lr * 72 + ks * 32 + lq * 8];
            acc[0] = __builtin_amdgcn_mfma_f32_16x16x32_bf16(a0, bb, acc[0], 0, 0, 0);
            acc[1] = __builtin_amdgcn_mfma_f32_16x16x32_bf16(a1, bb, acc[1], 0, 0, 0);
        }
        // (4) h update from scb (registers only)
        {
            const u16* sg = scb + (size_t)(dbh * 16 + c) * 4096 + (p0 + hp) * 64 + hn;
            uint2 q = *(const uint2*)sg;
            float dk = decay[dbh * 16 + c];
            hreg[0] = dk * hreg[0] + b2f(q.x & 0xffffu);
            hreg[1] = dk * hreg[1] + b2f(q.x >> 16);
            hreg[2] = dk * hreg[2] + b2f(q.y & 0xffffu);
            hreg[3] = dk * hreg[3] + b2f(q.y >> 16);
        }
        // (5) stage y' -> ybuf
        #pragma unroll
        for (int ti = 0; ti < 2; ti++)
            #pragma unroll
            for (int r = 0; r < 4; r++) {
                int t_l = w * 32 + ti * 16 + lq * 4 + r;
                ybuf[t_l * 20 + lr] = acc[ti][r];
            }
        __syncthreads();
        // (6) coalesced y RMW: thread = (t row, 8-p half)
        {
            int s = c * QC + rmw_t;
            int t = dir ? (L_ - 1 - s) : s;
            u16* yp = yo + ((size_t)b * L_ + t) * DIN + h * 64 + p0 + rmw_p;
            uint4 ov = *(const uint4*)yp;
            float of[8]; unpack8(ov, of);
            float nf[8];
            #pragma unroll
            for (int i = 0; i < 8; i++) nf[i] = of[i] + ybuf[rmw_t * 20 + rmw_p + i];
            *(uint4*)yp = pack8(nf);   // block owns (dir,b,h,p-slice) rows -- no races
        }
        __syncthreads();   // ybuf/hs/Csc reads done before next iteration overwrites
    }
}

// ---------- gate + RMSNorm -> bf16 (shift folded into the y reads) ----------
__global__ __launch_bounds__(256) void k_gate(const u16* __restrict__ xs, const u16* __restrict__ zx,
                                              const u16* __restrict__ y0, const u16* __restrict__ y1,
                                              const float* __restrict__ Dd,
                                              const float* __restrict__ nw, u16* __restrict__ yn) {
    int row = blockIdx.x, tid = threadIdx.x;
    int t = row & (L_ - 1);
    __shared__ float red[4];
    size_t base = (size_t)row * DIN;
    uint4 xv = ((const uint4*)(xs + base))[tid];
    uint4 zv = ((const uint4*)(zx + (size_t)row * NPAD))[tid];
    uint4 zero4 = {0u, 0u, 0u, 0u};
    uint4 a0 = (t > 0)      ? ((const uint4*)(y0 + base - DIN))[tid] : zero4;   // y_fwd[t-1]
    uint4 a1 = (t < L_ - 1) ? ((const uint4*)(y1 + base + DIN))[tid] : zero4;   // y_bwd[t+1]
    float sD = Dd[(size_t)row * 32 + (tid >> 3)];
    float xf[8], zf[8], f0[8], f1[8];
    unpack8(xv, xf); unpack8(zv, zf); unpack8(a0, f0); unpack8(a1, f1);
    int d0 = tid * 8;
    float g[8]; float ss = 0.f;
    #pragma unroll
    for (int i = 0; i < 8; i++) {
        float yv = f0[i] + f1[i] + xf[i] * sD;
        float z = zf[i];
        float gg = yv * (z / (1.f + __expf(-z)));
        g[i] = gg; ss += gg * gg;
    }
    for (int o = 32; o; o >>= 1) ss += __shfl_down(ss, o);
    if ((tid & 63) == 0) red[tid >> 6] = ss;
    __syncthreads();
    float tot = red[0] + red[1] + red[2] + red[3];
    float r = rsqrtf(tot * (1.f / DIN) + EPS);
    float o8[8];
    #pragma unroll
    for (int i = 0; i < 8; i++) o8[i] = g[i] * r * nw[d0 + i];
    ((uint4*)(yn + base))[tid] = pack8(o8);
}

// ---------- workspace layout (bytes) ----------
// LIFETIME NOTE (r8 bug): wo2/dec/fcb/Dd alias the u_bf region (OFF_U, 16 MB).
// Writers of those aliases MUST run after k_gemm_bt #1 consumes u_bf.
// k_prep_b (fcb, Dd) is therefore launched AFTER GEMM1.
#define OFF_U     ((size_t)0)                       // BL*DM bf16 (dead after GEMM1)
#define OFF_WIN   ((size_t)16777216)                // NPAD*DM bf16
#define OFF_WOUT  ((size_t)25690112)                // DM*DIN bf16
#define OFF_ZX    ((size_t)29884416)                // BL*NPAD bf16
#define OFF_XS    ((size_t)101187584)               // BL*DIN bf16
#define OFF_BC    ((size_t)134742016)               // BL*128 bf16 = 2 MB
#define OFF_DTA   ((size_t)138936320)               // (unused)
#define OFF_Y0    ((size_t)143130624)               // BL*DIN bf16
#define OFF_Y1    ((size_t)176685056)               // BL*DIN bf16
#define OFF_YN    ((size_t)210239488)               // BL*DIN bf16 (gate out); scb aliases (dead before k_gate writes yn)
// aliases inside dead OFF_U region (write-after-GEMM1 only):
#define OFF_WO2   OFF_U                             // 256*2048 f32 = 2 MB (k_chunk)
#define OFF_DEC   (OFF_U + 2097152)                 // 4096 f32 (k_chunk)
#define OFF_FCB   (OFF_U + 2113536)                 // NH*DIN bf16 = 128 KB (k_prep_b)
#define OFF_DD    (OFF_U + 2244608)                 // BL*32 f32 = 1 MB (k_prep_b)
#define OFF_SCB   OFF_YN                            // 4096*4096 bf16 = 33.5 MB
// total 243,793,920 bytes

extern "C" void kernel_launch(void* const* d_in, const int* in_sizes, int n_in,
                              void* d_out, int out_size, void* d_ws, size_t ws_size,
                              hipStream_t stream) {
    const float* x       = (const float*)d_in[0];
    const float* ln_g    = (const float*)d_in[1];
    const float* ln_b    = (const float*)d_in[2];
    const float* W_in    = (const float*)d_in[3];
    const float* conv_w  = (const float*)d_in[4];
    const float* conv_b  = (const float*)d_in[5];
    const float* dt_bias = (const float*)d_in[6];
    const float* A_log   = (const float*)d_in[7];
    const float* fc_D_w  = (const float*)d_in[8];
    const float* Dv      = (const float*)d_in[9];
    const float* norm_w  = (const float*)d_in[10];
    const float* W_out   = (const float*)d_in[11];

    char* ws = (char*)d_ws;
    u16*   u_bf  = (u16*)(ws + OFF_U);
    u16*   winb  = (u16*)(ws + OFF_WIN);
    u16*   woutb = (u16*)(ws + OFF_WOUT);
    u16*   zx    = (u16*)(ws + OFF_ZX);
    u16*   xs    = (u16*)(ws + OFF_XS);
    u16*   BCb   = (u16*)(ws + OFF_BC);
    u16*   y0b   = (u16*)(ws + OFF_Y0);
    u16*   y1b   = (u16*)(ws + OFF_Y1);
    u16*   ynb   = (u16*)(ws + OFF_YN);
    float* wo2   = (float*)(ws + OFF_WO2);
    float* dec   = (float*)(ws + OFF_DEC);
    u16*   fcb   = (u16*)(ws + OFF_FCB);
    float* Dd    = (float*)(ws + OFF_DD);
    u16*   scb   = (u16*)(ws + OFF_SCB);

    k_prep_a  <<<GP_LN + GP_WIN + GP_WOUT, 256, 0, stream>>>
              (x, ln_g, ln_b, u_bf, W_in, winb, W_out, woutb);
    k_gemm_bt <<<dim3(NPAD / 128, BL / 128), 256, 0, stream>>>(u_bf, winb, BL, NPAD, DM, 1, zx, NPAD, nullptr, nullptr);
    k_prep_b  <<<GP_FCD + GP_DZ, 256, 0, stream>>>(fc_D_w, fcb, Dv, Dd);
    k_conv    <<<dim3(CONV_DIM / 64, L_ / 256, B_), 256, 0, stream>>>(zx, conv_w, conv_b, xs, BCb);
    k_dproj   <<<dim3(BL / 32, 8), 256, 0, stream>>>(xs, fcb, Dd);
    k_chunk   <<<4096, 256, 0, stream>>>(xs, BCb, zx, dt_bias, A_log, y0b, y1b, wo2, dec, scb);
    k_hinter  <<<1024, 256, 0, stream>>>(BCb, wo2, dec, scb, y0b, y1b);
    k_gate    <<<BL, 256, 0, stream>>>(xs, zx, y0b, y1b, Dd, norm_w, ynb);
    k_gemm_bt <<<dim3(DM / 128, BL / 128), 256, 0, stream>>>(ynb, woutb, BL, DM, DIN, 0, nullptr, DM, (float*)d_out, x);
}

// Round 10
// 492.474 us; speedup vs baseline: 1.1102x; 1.1102x over previous
//
#include <hip/hip_runtime.h>
#include <stdint.h>

// ---- problem constants ----
#define B_   4
#define L_   2048
#define DM   1024
#define DIN  2048
#define NH   32
#define HD   64
#define DSTATE 64
#define DCONV  7
#define CONV_DIM 2176            // DIN + 2*DSTATE
#define DPROJ 4288               // 2*DIN + 2*DSTATE + 2*NH
#define NPAD 4352                // DPROJ padded to 128
#define BL   8192                // B_*L_
#define EPS  1e-5f
#define QC   128                 // scan chunk length
#define NCH  16                  // chunks per sequence

typedef unsigned short u16;
typedef unsigned int   u32;
typedef __bf16 bf16x8 __attribute__((ext_vector_type(8)));
typedef float  f32x4  __attribute__((ext_vector_type(4)));

__device__ __forceinline__ float b2f(u32 b) { return __uint_as_float(b << 16); }
__device__ __forceinline__ u16 f2b(float f) {
    u32 u = __float_as_uint(f);
    u32 r = (u + 0x7fffu + ((u >> 16) & 1u)) >> 16;
    return (u16)r;
}
__device__ __forceinline__ void unpack8(uint4 v, float* f) {
    f[0] = b2f(v.x & 0xffffu); f[1] = b2f(v.x >> 16);
    f[2] = b2f(v.y & 0xffffu); f[3] = b2f(v.y >> 16);
    f[4] = b2f(v.z & 0xffffu); f[5] = b2f(v.z >> 16);
    f[6] = b2f(v.w & 0xffffu); f[7] = b2f(v.w >> 16);
}
__device__ __forceinline__ uint4 pack8(const float* f) {
    uint4 v;
    v.x = (u32)f2b(f[0]) | ((u32)f2b(f[1]) << 16);
    v.y = (u32)f2b(f[2]) | ((u32)f2b(f[3]) << 16);
    v.z = (u32)f2b(f[4]) | ((u32)f2b(f[5]) << 16);
    v.w = (u32)f2b(f[6]) | ((u32)f2b(f[7]) << 16);
    return v;
}
// skewed LDS index for transposed tiles: row-stride 136 u16 + 8-u16 skew per 8 rows.
__device__ __forceinline__ int xts(int p, int s) { return p * 136 + ((p >> 3) << 3) + s; }
// async global->LDS, 16B per lane; lds base must be wave-uniform (HW adds lane*16)
__device__ __forceinline__ void gload_lds16(const u16* g, u16* l) {
    __builtin_amdgcn_global_load_lds((const __attribute__((address_space(1))) void*)g,
                                     (__attribute__((address_space(3))) void*)l, 16, 0, 0);
}

// ---------- prep A: layernorm + W_in/W_out cvt (targets disjoint from u_bf alias region) ----------
// MUST run before GEMM1. block ranges: [0,8192) ln ; [8192,12544) cvt_win ; [12544,14592) cvt_wout
#define GP_LN    8192
#define GP_WIN   4352
#define GP_WOUT  2048
#define GP_FCD   64
#define GP_DZ    1024
__global__ __launch_bounds__(256) void k_prep_a(const float* __restrict__ x, const float* __restrict__ g,
                                                const float* __restrict__ be, u16* __restrict__ u,
                                                const float* __restrict__ Wi, u16* __restrict__ wib,
                                                const float* __restrict__ Wo, u16* __restrict__ wob) {
    int bb = blockIdx.x, tid = threadIdx.x;
    if (bb < GP_LN) {
        int row = bb;
        const float4* xr = (const float4*)(x + (size_t)row * DM);
        float4 v = xr[tid];
        float s1 = v.x + v.y + v.z + v.w;
        float s2 = v.x * v.x + v.y * v.y + v.z * v.z + v.w * v.w;
        for (int o = 32; o; o >>= 1) { s1 += __shfl_down(s1, o); s2 += __shfl_down(s2, o); }
        __shared__ float ls1[4], ls2[4];
        int w = tid >> 6;
        if ((tid & 63) == 0) { ls1[w] = s1; ls2[w] = s2; }
        __syncthreads();
        float t1 = ls1[0] + ls1[1] + ls1[2] + ls1[3];
        float t2 = ls2[0] + ls2[1] + ls2[2] + ls2[3];
        float mu = t1 * (1.f / DM);
        float var = t2 * (1.f / DM) - mu * mu;
        float rs = rsqrtf(var + EPS);
        float4 gv = ((const float4*)g)[tid];
        float4 bv = ((const float4*)be)[tid];
        float o0 = (v.x - mu) * rs * gv.x + bv.x;
        float o1 = (v.y - mu) * rs * gv.y + bv.y;
        float o2 = (v.z - mu) * rs * gv.z + bv.z;
        float o3 = (v.w - mu) * rs * gv.w + bv.w;
        uint2 p;
        p.x = (u32)f2b(o0) | ((u32)f2b(o1) << 16);
        p.y = (u32)f2b(o2) | ((u32)f2b(o3) << 16);
        ((uint2*)(u + (size_t)row * DM))[tid] = p;
    } else if (bb < GP_LN + GP_WIN) {
        int idx4 = ((bb - GP_LN) * 256 + tid) * 4;      // over NPAD*DM
        int n = idx4 >> 10, col = idx4 & 1023;
        uint2 p = {0u, 0u};
        if (n < DPROJ) {
            float4 v = *(const float4*)(Wi + (size_t)n * DM + col);
            p.x = (u32)f2b(v.x) | ((u32)f2b(v.y) << 16);
            p.y = (u32)f2b(v.z) | ((u32)f2b(v.w) << 16);
        }
        *(uint2*)(wib + idx4) = p;
    } else {
        int idx4 = ((bb - GP_LN - GP_WIN) * 256 + tid) * 4;   // over DM*DIN
        float4 v = *(const float4*)(Wo + idx4);
        uint2 p;
        p.x = (u32)f2b(v.x) | ((u32)f2b(v.y) << 16);
        p.y = (u32)f2b(v.z) | ((u32)f2b(v.w) << 16);
        *(uint2*)(wob + idx4) = p;
    }
}

// ---------- prep B: fc_D cvt + Dd seed. WRITES INTO DEAD u_bf REGION -> must run AFTER GEMM1 ----------
__global__ __launch_bounds__(256) void k_prep_b(const float* __restrict__ Wf, u16* __restrict__ fcb,
                                                const float* __restrict__ Dv, float* __restrict__ Dd) {
    int bb = blockIdx.x, tid = threadIdx.x;
    if (bb < GP_FCD) {
        int idx4 = (bb * 256 + tid) * 4;                // over NH*DIN
        float4 v = *(const float4*)(Wf + idx4);
        uint2 p;
        p.x = (u32)f2b(v.x) | ((u32)f2b(v.y) << 16);
        p.y = (u32)f2b(v.z) | ((u32)f2b(v.w) << 16);
        *(uint2*)(fcb + idx4) = p;
    } else {
        int idx = (bb - GP_FCD) * 256 + tid;            // over BL*32
        Dd[idx] = Dv[idx & 31];
    }
}

// ---------- bf16 MFMA GEMM, C[m,n] = sum_k A[m,k]*B[n,k]  (B^T layout) ----------
// 128x128 tile, 2-barrier K-loop, global_load_lds width=16 staging (proven m97
// structure). 256^2 deep-pipeline variants tried in rounds 1-4 all regressed
// (103-120 us, MfmaUtil <30%) -- do not revisit without new evidence.
// Cross-acquisition noise ~+/-10% (95.4 us r0/r6 vs ~110-112 us r5/r7).
__global__ __launch_bounds__(256) void k_gemm_bt(const u16* __restrict__ A, const u16* __restrict__ Bw,
                                                 int M, int N, int K, int out_bf16,
                                                 u16* __restrict__ obf, int ldo,
                                                 float* __restrict__ ofp, const float* __restrict__ res) {
    __shared__ __align__(16) u16 As[128 * 64];
    __shared__ __align__(16) u16 Bs[128 * 64];
    int tid = threadIdx.x;
    int m0 = blockIdx.y * 128, n0 = blockIdx.x * 128;
    int w = tid >> 6, lane = tid & 63;
    int wm = (w >> 1) * 64, wn = (w & 1) * 64;
    int lr = lane & 15, lq = lane >> 4;

    f32x4 acc[4][4];
    #pragma unroll
    for (int i = 0; i < 4; i++)
        #pragma unroll
        for (int j = 0; j < 4; j++) acc[i][j] = (f32x4){0.f, 0.f, 0.f, 0.f};

    for (int kt = 0; kt < K; kt += 64) {
        #pragma unroll
        for (int it = 0; it < 4; it++) {
            int s_idx = it * 256 + tid;
            int row = s_idx >> 3;
            int kcg = (s_idx & 7) ^ (row & 7);            // swizzled source chunk
            u16* lbase_a = &As[(it * 256 + w * 64) * 8];  // wave-uniform
            u16* lbase_b = &Bs[(it * 256 + w * 64) * 8];
            gload_lds16(A + (size_t)(m0 + row) * K + kt + kcg * 8, lbase_a);
            gload_lds16(Bw + (size_t)(n0 + row) * K + kt + kcg * 8, lbase_b);
        }
        __syncthreads();
        #pragma unroll
        for (int kk = 0; kk < 2; kk++) {
            bf16x8 af[4], bfr[4];
            #pragma unroll
            for (int i = 0; i < 4; i++) {
                int row = wm + 16 * i + lr;
                af[i] = *(const bf16x8*)&As[row * 64 + (((kk * 4 + lq)) ^ (row & 7)) * 8];
            }
            #pragma unroll
            for (int j = 0; j < 4; j++) {
                int row = wn + 16 * j + lr;
                bfr[j] = *(const bf16x8*)&Bs[row * 64 + (((kk * 4 + lq)) ^ (row & 7)) * 8];
            }
            #pragma unroll
            for (int i = 0; i < 4; i++)
                #pragma unroll
                for (int j = 0; j < 4; j++)
                    acc[i][j] = __builtin_amdgcn_mfma_f32_16x16x32_bf16(af[i], bfr[j], acc[i][j], 0, 0, 0);
        }
        __syncthreads();
    }
    #pragma unroll
    for (int i = 0; i < 4; i++) {
        #pragma unroll
        for (int j = 0; j < 4; j++) {
            #pragma unroll
            for (int rr = 0; rr < 4; rr++) {
                int m = m0 + wm + 16 * i + lq * 4 + rr;
                int n = n0 + wn + 16 * j + lr;
                float v = acc[i][j][rr];
                if (out_bf16) obf[(size_t)m * ldo + n] = f2b(v);
                else          ofp[(size_t)m * ldo + n] = v + res[(size_t)m * ldo + n];
            }
        }
    }
}

// ---------- D-projection GEMM, split-K x8: Dd[m][h] += partial dot(xs[m,:], fc_D_w[h,:]) ----------
__global__ __launch_bounds__(256) void k_dproj(const u16* __restrict__ xs, const u16* __restrict__ fcb,
                                               float* __restrict__ Dd) {
    __shared__ __align__(16) u16 As[32 * 72];
    __shared__ __align__(16) u16 Bs[32 * 72];
    int tid = threadIdx.x;
    int m0 = blockIdx.x * 32;
    int k0 = blockIdx.y * 256;                          // 8 K-slices of 256
    int w = tid >> 6, lane = tid & 63, lr = lane & 15, lq = lane >> 4;
    int mt = (w & 1) * 16, nt = (w >> 1) * 16;
    int r = tid >> 3, kc = tid & 7;
    f32x4 acc = (f32x4){0.f, 0.f, 0.f, 0.f};
    for (int kt = k0; kt < k0 + 256; kt += 64) {
        *(uint4*)&As[r * 72 + kc * 8] = *(const uint4*)(xs + (size_t)(m0 + r) * DIN + kt + kc * 8);
        *(uint4*)&Bs[r * 72 + kc * 8] = *(const uint4*)(fcb + (size_t)r * DIN + kt + kc * 8);
        __syncthreads();
        #pragma unroll
        for (int ks = 0; ks < 2; ks++) {
            bf16x8 a = *(const bf16x8*)&As[(mt + lr) * 72 + ks * 32 + lq * 8];
            bf16x8 b = *(const bf16x8*)&Bs[(nt + lr) * 72 + ks * 32 + lq * 8];
            acc = __builtin_amdgcn_mfma_f32_16x16x32_bf16(a, b, acc, 0, 0, 0);
        }
        __syncthreads();
    }
    #pragma unroll
    for (int rr = 0; rr < 4; rr++) {
        int m = m0 + mt + lq * 4 + rr;
        int n = nt + lr;
        atomicAdd(&Dd[(size_t)m * 32 + n], acc[rr]);
    }
}

// ---------- depthwise conv7 (same-pad) + bias + SiLU, split xs / BC(bf16) ----------
__global__ __launch_bounds__(256) void k_conv(const u16* __restrict__ zx, const float* __restrict__ cw,
                                              const float* __restrict__ cb, u16* __restrict__ xs,
                                              u16* __restrict__ BCb) {
    __shared__ u16 sh[262 * 64];
    int c0 = blockIdx.x * 64, t0 = blockIdx.y * 256, b = blockIdx.z;
    int tid = threadIdx.x;
    int c = tid & 63, tg = tid >> 6;
    for (int it = 0; it < 66; it++) {
        int r = it * 4 + tg;
        if (r < 262) {
            int t = t0 + r - 3;
            u16 v = 0;
            if (t >= 0 && t < L_) v = zx[(size_t)(b * L_ + t) * NPAD + DIN + c0 + c];
            sh[r * 64 + c] = v;
        }
    }
    float wgt[7];
    #pragma unroll
    for (int k = 0; k < 7; k++) wgt[k] = cw[(c0 + c) * 7 + k];
    float bias = cb[c0 + c];
    __syncthreads();
    int cg = c0 + c;
    for (int tt = 0; tt < 64; tt++) {
        int tl = tt * 4 + tg;
        float a = bias;
        #pragma unroll
        for (int k = 0; k < 7; k++) a += b2f(sh[(tl + k) * 64 + c]) * wgt[k];
        float v = a / (1.f + __expf(-a));   // silu
        size_t row = (size_t)b * L_ + (t0 + tl);
        if (cg < DIN) xs[row * DIN + cg] = f2b(v);
        else          BCb[row * 128 + (cg - DIN)] = f2b(v);   // B at [0,64), C at [64,128), bf16
    }
}

// ======================================================================
// Chunked SSD scan (intra-chunk + chunk-state + inline dt): block = (dir,b,h,chunk).
// R5: outputs staged through dead LDS, coalesced uint4 stores.
// R7: Y and S_c MFMA groups merged before a single barrier (tail 4 -> 2 barriers).
// ======================================================================
__global__ __launch_bounds__(256) void k_chunk(const u16* __restrict__ xs, const u16* __restrict__ BCb,
                                               const u16* __restrict__ zx, const float* __restrict__ dt_bias,
                                               const float* __restrict__ A_log, u16* __restrict__ y0,
                                               u16* __restrict__ y1, float* __restrict__ wout,
                                               float* __restrict__ decay, u16* __restrict__ scb) {
    __shared__ __align__(16) u16 ab[18432];      // Cs [0,9216) stride 72, Bs [9216,18432); S overlays (skewed 136); y-stage overlays [t][72]
    __shared__ __align__(16) u16 XT[8768];       // X^T [p][s] skewed
    __shared__ __align__(16) u16 BT[8768];       // B^T [n][s] skewed; scb-stage overlays [p][72]
    __shared__ __align__(16) float dts_s[128];
    __shared__ __align__(16) float lda_s[128];
    __shared__ __align__(16) float wend[128];
    __shared__ __align__(16) double cumd[128];

    const int blk = blockIdx.x;
    const int c = blk & 15, dbh = blk >> 4;
    const int h = dbh & 31, b = (dbh >> 5) & 3, dir = dbh >> 7;
    const int tid = threadIdx.x, w = tid >> 6, lane = tid & 63, lr = lane & 15, lq = lane >> 4;
    const int s0 = c * QC;
    u16* yo = dir ? y1 : y0;

    if (tid < 128) {   // inline dt2 / log-dA
        int s = s0 + tid;
        int t = dir ? (L_ - 1 - s) : s;
        float draw = b2f(zx[(size_t)(b * L_ + t) * NPAD + (DIN + CONV_DIM) + dir * 32 + h]);
        float xb = draw + dt_bias[h];
        float dt2 = (xb > 20.f) ? xb : log1pf(__expf(xb));
        dts_s[tid] = dt2;
        lda_s[tid] = -__expf(A_log[h]) * dt2;
    }
    {   // stage Cs, Bs (bf16 row-major), BT, XT (transposed, skewed)
        int sl0 = tid >> 3, ng = (tid & 7) * 8;
        #pragma unroll
        for (int it = 0; it < 4; it++) {
            int sl = sl0 + it * 32;
            int s = s0 + sl;
            int t = dir ? (L_ - 1 - s) : s;
            size_t row = (size_t)b * L_ + t;
            const u16* bcr = BCb + row * 128;
            uint4 cv = *(const uint4*)(bcr + 64 + ng);
            *(uint4*)&ab[sl * 72 + ng] = cv;
            uint4 pb = *(const uint4*)(bcr + ng);
            *(uint4*)&ab[9216 + sl * 72 + ng] = pb;
            u16 bh[8] = {(u16)(pb.x & 0xffffu), (u16)(pb.x >> 16), (u16)(pb.y & 0xffffu), (u16)(pb.y >> 16),
                         (u16)(pb.z & 0xffffu), (u16)(pb.z >> 16), (u16)(pb.w & 0xffffu), (u16)(pb.w >> 16)};
            #pragma unroll
            for (int i = 0; i < 8; i++) BT[(ng + i) * 136 + ng + sl] = bh[i];   // skew = ng
            uint4 xv = *(const uint4*)(xs + row * DIN + h * 64 + ng);
            u16 xh[8] = {(u16)(xv.x & 0xffffu), (u16)(xv.x >> 16), (u16)(xv.y & 0xffffu), (u16)(xv.y >> 16),
                         (u16)(xv.z & 0xffffu), (u16)(xv.z >> 16), (u16)(xv.w & 0xffffu), (u16)(xv.w >> 16)};
            #pragma unroll
            for (int i = 0; i < 8; i++) XT[(ng + i) * 136 + ng + sl] = xh[i];   // skew = ng
        }
    }
    __syncthreads();
    if (w == 0) {   // double-precision inclusive prefix of log-dA (wave 0)
        double v0 = (double)lda_s[lane];
        double v1 = (double)lda_s[64 + lane];
        #pragma unroll
        for (int o = 1; o < 64; o <<= 1) {
            double t0 = __shfl_up(v0, o);
            double t1 = __shfl_up(v1, o);
            if (lane >= o) { v0 += t0; v1 += t1; }
        }
        double tot0 = __shfl(v0, 63);
        cumd[lane] = v0;
        cumd[64 + lane] = tot0 + v1;
    }
    // G = C * B^T  (wave w owns t-rows [w*32, w*32+32))
    bf16x8 af[2][2];
    #pragma unroll
    for (int ti = 0; ti < 2; ti++)
        #pragma unroll
        for (int ks = 0; ks < 2; ks++)
            af[ti][ks] = *(const bf16x8*)&ab[(w * 32 + ti * 16 + lr) * 72 + ks * 32 + lq * 8];
    f32x4 accg[2][8];
    #pragma unroll
    for (int ti = 0; ti < 2; ti++)
        #pragma unroll
        for (int si = 0; si < 8; si++) accg[ti][si] = (f32x4){0.f, 0.f, 0.f, 0.f};
    #pragma unroll
    for (int si = 0; si < 8; si++)
        #pragma unroll
        for (int ks = 0; ks < 2; ks++) {
            bf16x8 bf = *(const bf16x8*)&ab[9216 + (si * 16 + lr) * 72 + ks * 32 + lq * 8];
            accg[0][si] = __builtin_amdgcn_mfma_f32_16x16x32_bf16(af[0][ks], bf, accg[0][si], 0, 0, 0);
            accg[1][si] = __builtin_amdgcn_mfma_f32_16x16x32_bf16(af[1][ks], bf, accg[1][si], 0, 0, 0);
        }
    __syncthreads();   // all G frag reads done; cumd ready
    // wend[s] = exp(cum[127]-cum[s])*dt[s]  (for chunk-state); visible after next barrier
    if (tid < 128) wend[tid] = __expf((float)(cumd[127] - cumd[tid])) * dts_s[tid];
    // S = M .* G  -> overlay into ab (skewed stride 136)
    {
        double cumt_d[8];
        #pragma unroll
        for (int ti = 0; ti < 2; ti++)
            #pragma unroll
            for (int r = 0; r < 4; r++) cumt_d[ti * 4 + r] = cumd[w * 32 + ti * 16 + lq * 4 + r];
        double cums_d[8]; float dts_l[8];
        #pragma unroll
        for (int si = 0; si < 8; si++) { cums_d[si] = cumd[si * 16 + lr]; dts_l[si] = dts_s[si * 16 + lr]; }
        #pragma unroll
        for (int ti = 0; ti < 2; ti++)
            #pragma unroll
            for (int si = 0; si < 8; si++)
                #pragma unroll
                for (int r = 0; r < 4; r++) {
                    int t_l = w * 32 + ti * 16 + lq * 4 + r;
                    int s_l = si * 16 + lr;
                    float v = 0.f;
                    if (s_l <= t_l)
                        v = __expf((float)(cumt_d[ti * 4 + r] - cums_d[si])) * dts_l[si] * accg[ti][si][r];
                    ab[xts(t_l, s_l)] = f2b(v);
                }
    }
    __syncthreads();
    // Y_intra = S * X^T
    f32x4 acc[2][4];
    #pragma unroll
    for (int ti = 0; ti < 2; ti++)
        #pragma unroll
        for (int pj = 0; pj < 4; pj++) acc[ti][pj] = (f32x4){0.f, 0.f, 0.f, 0.f};
    #pragma unroll
    for (int ks = 0; ks < 4; ks++) {
        bf16x8 a0 = *(const bf16x8*)&ab[xts(w * 32 + lr, ks * 32 + lq * 8)];
        bf16x8 a1 = *(const bf16x8*)&ab[xts(w * 32 + 16 + lr, ks * 32 + lq * 8)];
        #pragma unroll
        for (int pj = 0; pj < 4; pj++) {
            bf16x8 bf = *(const bf16x8*)&XT[xts(pj * 16 + lr, ks * 32 + lq * 8)];
            acc[0][pj] = __builtin_amdgcn_mfma_f32_16x16x32_bf16(a0, bf, acc[0][pj], 0, 0, 0);
            acc[1][pj] = __builtin_amdgcn_mfma_f32_16x16x32_bf16(a1, bf, acc[1][pj], 0, 0, 0);
        }
    }
    // chunk state S_c[p][n] = sum_s wend[s]*x[s][p]*B[s][n]  (merged: reads stable XT/BT/wend)
    f32x4 accs[4];
    #pragma unroll
    for (int nj = 0; nj < 4; nj++) accs[nj] = (f32x4){0.f, 0.f, 0.f, 0.f};
    #pragma unroll
    for (int ks = 0; ks < 4; ks++) {
        uint4 xv = *(const uint4*)&XT[xts(w * 16 + lr, ks * 32 + lq * 8)];
        float xf[8]; unpack8(xv, xf);
        float4 w0 = *(const float4*)&wend[ks * 32 + lq * 8];
        float4 w1 = *(const float4*)&wend[ks * 32 + lq * 8 + 4];
        float fs[8] = {xf[0]*w0.x, xf[1]*w0.y, xf[2]*w0.z, xf[3]*w0.w,
                       xf[4]*w1.x, xf[5]*w1.y, xf[6]*w1.z, xf[7]*w1.w};
        bf16x8 a = __builtin_bit_cast(bf16x8, pack8(fs));
        #pragma unroll
        for (int nj = 0; nj < 4; nj++) {
            bf16x8 bb = *(const bf16x8*)&BT[xts(nj * 16 + lr, ks * 32 + lq * 8)];
            accs[nj] = __builtin_amdgcn_mfma_f32_16x16x32_bf16(a, bb, accs[nj], 0, 0, 0);
        }
    }
    // ---- single barrier: all LDS reads (S/XT/BT) complete; stage both outputs ----
    __syncthreads();
    #pragma unroll
    for (int ti = 0; ti < 2; ti++)
        #pragma unroll
        for (int pj = 0; pj < 4; pj++)
            #pragma unroll
            for (int r = 0; r < 4; r++) {
                int t_l = w * 32 + ti * 16 + lq * 4 + r;
                ab[t_l * 72 + pj * 16 + lr] = f2b(acc[ti][pj][r]);   // Y: [t][p] stride 72
            }
    #pragma unroll
    for (int nj = 0; nj < 4; nj++)
        #pragma unroll
        for (int r = 0; r < 4; r++) {
            int p = w * 16 + lq * 4 + r, n = nj * 16 + lr;
            BT[p * 72 + n] = f2b(accs[nj][r]);                       // S_c: [p][n] stride 72
        }
    __syncthreads();
    // ---- coalesced stores ----
    #pragma unroll
    for (int k2 = 0; k2 < 4; k2++) {
        int c2 = k2 * 256 + tid;
        int t_l = c2 >> 3, p0 = (c2 & 7) * 8;
        int s = s0 + t_l;
        int t = dir ? (L_ - 1 - s) : s;
        *(uint4*)(yo + ((size_t)b * L_ + t) * DIN + h * 64 + p0) = *(const uint4*)&ab[t_l * 72 + p0];
    }
    #pragma unroll
    for (int k2 = 0; k2 < 2; k2++) {
        int c2 = k2 * 256 + tid;
        int p = c2 >> 3, n0 = (c2 & 7) * 8;
        *(uint4*)(scb + (size_t)blk * 4096 + p * 64 + n0) = *(const uint4*)&BT[p * 72 + n0];
    }
    if (tid < 128) wout[dbh * 2048 + s0 + tid] = __expf((float)cumd[tid]);
    if (tid == 0)  decay[blk] = __expf((float)cumd[127]);
}

// ---------- h-state scan (barrier-free): rewrites scb slots in place with h_in per chunk ----------
// elementwise recurrence h = decay*h + S_c over 16 chunks; 4 blocks per dbh
// (1024 blocks) for 4x TLP; each thread owns 4 slots (8B coalesced).
// NOTE (r9): merging this into k_inter (serial chunks per block) was tried and
// REGRESSED badly (97 us, MfmaUtil 1.7%) -- chunk-parallelism of k_inter is
// worth far more than the 67 MB h-traffic saved. Do not re-merge.
__global__ __launch_bounds__(256) void k_hscan(const float* __restrict__ decay, u16* __restrict__ scb) {
    int bid = blockIdx.x;                 // 1024 = 256 dbh x 4 slices
    int dbh = bid >> 2, ps = bid & 3;
    int tid = threadIdx.x;
    u16* base = scb + (size_t)dbh * 16 * 4096 + ps * 1024 + tid * 4;
    float h0 = 0.f, h1 = 0.f, h2 = 0.f, h3 = 0.f;
    for (int c = 0; c < NCH; c++) {
        u16* sg = base + (size_t)c * 4096;
        uint2 q = *(const uint2*)sg;
        float s0 = b2f(q.x & 0xffffu), s1 = b2f(q.x >> 16);
        float s2 = b2f(q.y & 0xffffu), s3 = b2f(q.y >> 16);
        uint2 o;
        o.x = (u32)f2b(h0) | ((u32)f2b(h1) << 16);
        o.y = (u32)f2b(h2) | ((u32)f2b(h3) << 16);
        *(uint2*)sg = o;                  // h entering chunk c
        float dk = decay[dbh * 16 + c];
        h0 = dk * h0 + s0; h1 = dk * h1 + s1;
        h2 = dk * h2 + s2; h3 = dk * h3 + s3;
    }
}

// ---------- inter-chunk contribution (parallel): y += (wout.*C) * h_in^T ----------
// R5: y-RMW staged as f32 through LDS (identical arithmetic: f32 add then one
// bf16 round), coalesced uint4 load+store. Chunk-parallel: 4096 blocks.
__global__ __launch_bounds__(256) void k_inter(const u16* __restrict__ BCb, const float* __restrict__ wout,
                                               const u16* __restrict__ hin, u16* __restrict__ y0,
                                               u16* __restrict__ y1) {
    __shared__ __align__(16) u16 smem[18432];        // Csc [0,9216) stride 72; hs [9216,13824); f32 [128][68] y-stage overlays
    u16* Csc = smem;
    u16* hs  = smem + 9216;
    float* fsm = (float*)smem;
    const int blk = blockIdx.x;
    const int c = blk & 15, dbh = blk >> 4;
    const int h = dbh & 31, b = (dbh >> 5) & 3, dir = dbh >> 7;
    const int tid = threadIdx.x, w = tid >> 6, lane = tid & 63, lr = lane & 15, lq = lane >> 4;
    u16* yo = dir ? y1 : y0;

    {   // stage h_in (p-major 64x64 -> padded rows)
        int g = tid * 16, p = g >> 6, n = g & 63;
        const u16* hg = hin + (size_t)blk * 4096 + g;
        *(uint4*)&hs[p * 72 + n]     = *(const uint4*)hg;
        *(uint4*)&hs[p * 72 + n + 8] = *(const uint4*)(hg + 8);
    }
    const int sl0 = tid >> 3, ng = (tid & 7) * 8;
    #pragma unroll
    for (int it = 0; it < 4; it++) {
        int sl = sl0 + it * 32;
        int s = c * QC + sl;
        int t = dir ? (L_ - 1 - s) : s;
        const u16* bcr = BCb + ((size_t)b * L_ + t) * 128 + 64 + ng;
        float sc = wout[dbh * 2048 + s];
        uint4 cv = *(const uint4*)bcr;
        float cf[8]; unpack8(cv, cf);
        float f[8] = {cf[0]*sc, cf[1]*sc, cf[2]*sc, cf[3]*sc, cf[4]*sc, cf[5]*sc, cf[6]*sc, cf[7]*sc};
        *(uint4*)&Csc[sl * 72 + ng] = pack8(f);
    }
    __syncthreads();
    f32x4 acc[2][4];
    #pragma unroll
    for (int ti = 0; ti < 2; ti++)
        #pragma unroll
        for (int pj = 0; pj < 4; pj++) acc[ti][pj] = (f32x4){0.f, 0.f, 0.f, 0.f};
    #pragma unroll
    for (int ks = 0; ks < 2; ks++) {
        bf16x8 a0 = *(const bf16x8*)&Csc[(w * 32 + lr) * 72 + ks * 32 + lq * 8];
        bf16x8 a1 = *(const bf16x8*)&Csc[(w * 32 + 16 + lr) * 72 + ks * 32 + lq * 8];
        #pragma unroll
        for (int pj = 0; pj < 4; pj++) {
            bf16x8 bb = *(const bf16x8*)&hs[(pj * 16 + lr) * 72 + ks * 32 + lq * 8];
            acc[0][pj] = __builtin_amdgcn_mfma_f32_16x16x32_bf16(a0, bb, acc[0][pj], 0, 0, 0);
            acc[1][pj] = __builtin_amdgcn_mfma_f32_16x16x32_bf16(a1, bb, acc[1][pj], 0, 0, 0);
        }
    }
    // ---- f32 LDS transpose (smem dead after barrier), then coalesced uint4 RMW ----
    __syncthreads();                                 // Csc/hs reads complete
    #pragma unroll
    for (int ti = 0; ti < 2; ti++)
        #pragma unroll
        for (int pj = 0; pj < 4; pj++)
            #pragma unroll
            for (int r = 0; r < 4; r++) {
                int t_l = w * 32 + ti * 16 + lq * 4 + r;
                fsm[t_l * 68 + pj * 16 + lr] = acc[ti][pj][r];   // [t][p] stride 68 f32
            }
    __syncthreads();
    #pragma unroll
    for (int k2 = 0; k2 < 4; k2++) {
        int c2 = k2 * 256 + tid;
        int t_l = c2 >> 3, p0 = (c2 & 7) * 8;
        int s = c * QC + t_l;
        int t = dir ? (L_ - 1 - s) : s;
        u16* yp = yo + ((size_t)b * L_ + t) * DIN + h * 64 + p0;
        uint4 ov = *(const uint4*)yp;
        float of[8]; unpack8(ov, of);
        const float4 v0 = *(const float4*)&fsm[t_l * 68 + p0];
        const float4 v1 = *(const float4*)&fsm[t_l * 68 + p0 + 4];
        float nf[8] = {of[0] + v0.x, of[1] + v0.y, of[2] + v0.z, of[3] + v0.w,
                       of[4] + v1.x, of[5] + v1.y, of[6] + v1.z, of[7] + v1.w};
        *(uint4*)yp = pack8(nf);                      // RMW own rows only — no races
    }
}

// ---------- gate + RMSNorm -> bf16 (shift folded into the y reads) ----------
__global__ __launch_bounds__(256) void k_gate(const u16* __restrict__ xs, const u16* __restrict__ zx,
                                              const u16* __restrict__ y0, const u16* __restrict__ y1,
                                              const float* __restrict__ Dd,
                                              const float* __restrict__ nw, u16* __restrict__ yn) {
    int row = blockIdx.x, tid = threadIdx.x;
    int t = row & (L_ - 1);
    __shared__ float red[4];
    size_t base = (size_t)row * DIN;
    uint4 xv = ((const uint4*)(xs + base))[tid];
    uint4 zv = ((const uint4*)(zx + (size_t)row * NPAD))[tid];
    uint4 zero4 = {0u, 0u, 0u, 0u};
    uint4 a0 = (t > 0)      ? ((const uint4*)(y0 + base - DIN))[tid] : zero4;   // y_fwd[t-1]
    uint4 a1 = (t < L_ - 1) ? ((const uint4*)(y1 + base + DIN))[tid] : zero4;   // y_bwd[t+1]
    float sD = Dd[(size_t)row * 32 + (tid >> 3)];
    float xf[8], zf[8], f0[8], f1[8];
    unpack8(xv, xf); unpack8(zv, zf); unpack8(a0, f0); unpack8(a1, f1);
    int d0 = tid * 8;
    float g[8]; float ss = 0.f;
    #pragma unroll
    for (int i = 0; i < 8; i++) {
        float yv = f0[i] + f1[i] + xf[i] * sD;
        float z = zf[i];
        float gg = yv * (z / (1.f + __expf(-z)));
        g[i] = gg; ss += gg * gg;
    }
    for (int o = 32; o; o >>= 1) ss += __shfl_down(ss, o);
    if ((tid & 63) == 0) red[tid >> 6] = ss;
    __syncthreads();
    float tot = red[0] + red[1] + red[2] + red[3];
    float r = rsqrtf(tot * (1.f / DIN) + EPS);
    float o8[8];
    #pragma unroll
    for (int i = 0; i < 8; i++) o8[i] = g[i] * r * nw[d0 + i];
    ((uint4*)(yn + base))[tid] = pack8(o8);
}

// ---------- workspace layout (bytes) ----------
// LIFETIME NOTE: wo2/dec/fcb/Dd alias the u_bf region (OFF_U, 16 MB).
// Writers of those aliases MUST run after k_gemm_bt #1 consumes u_bf
// (k_prep_b is launched after GEMM1 for this reason; r8 bug).
#define OFF_U     ((size_t)0)                       // BL*DM bf16 (dead after GEMM1)
#define OFF_WIN   ((size_t)16777216)                // NPAD*DM bf16
#define OFF_WOUT  ((size_t)25690112)                // DM*DIN bf16
#define OFF_ZX    ((size_t)29884416)                // BL*NPAD bf16
#define OFF_XS    ((size_t)101187584)               // BL*DIN bf16
#define OFF_BC    ((size_t)134742016)               // BL*128 bf16 = 2 MB
#define OFF_DTA   ((size_t)138936320)               // (unused)
#define OFF_Y0    ((size_t)143130624)               // BL*DIN bf16
#define OFF_Y1    ((size_t)176685056)               // BL*DIN bf16
#define OFF_YN    ((size_t)210239488)               // BL*DIN bf16 (gate out); scb aliases (dead before k_gate writes yn)
// aliases inside dead OFF_U region (write-after-GEMM1 only):
#define OFF_WO2   OFF_U                             // 256*2048 f32 = 2 MB (k_chunk)
#define OFF_DEC   (OFF_U + 2097152)                 // 4096 f32 (k_chunk)
#define OFF_FCB   (OFF_U + 2113536)                 // NH*DIN bf16 = 128 KB (k_prep_b)
#define OFF_DD    (OFF_U + 2244608)                 // BL*32 f32 = 1 MB (k_prep_b)
#define OFF_SCB   OFF_YN                            // 4096*4096 bf16 = 33.5 MB (S_c -> h_in in place)
// total 243,793,920 bytes

extern "C" void kernel_launch(void* const* d_in, const int* in_sizes, int n_in,
                              void* d_out, int out_size, void* d_ws, size_t ws_size,
                              hipStream_t stream) {
    const float* x       = (const float*)d_in[0];
    const float* ln_g    = (const float*)d_in[1];
    const float* ln_b    = (const float*)d_in[2];
    const float* W_in    = (const float*)d_in[3];
    const float* conv_w  = (const float*)d_in[4];
    const float* conv_b  = (const float*)d_in[5];
    const float* dt_bias = (const float*)d_in[6];
    const float* A_log   = (const float*)d_in[7];
    const float* fc_D_w  = (const float*)d_in[8];
    const float* Dv      = (const float*)d_in[9];
    const float* norm_w  = (const float*)d_in[10];
    const float* W_out   = (const float*)d_in[11];

    char* ws = (char*)d_ws;
    u16*   u_bf  = (u16*)(ws + OFF_U);
    u16*   winb  = (u16*)(ws + OFF_WIN);
    u16*   woutb = (u16*)(ws + OFF_WOUT);
    u16*   zx    = (u16*)(ws + OFF_ZX);
    u16*   xs    = (u16*)(ws + OFF_XS);
    u16*   BCb   = (u16*)(ws + OFF_BC);
    u16*   y0b   = (u16*)(ws + OFF_Y0);
    u16*   y1b   = (u16*)(ws + OFF_Y1);
    u16*   ynb   = (u16*)(ws + OFF_YN);
    float* wo2   = (float*)(ws + OFF_WO2);
    float* dec   = (float*)(ws + OFF_DEC);
    u16*   fcb   = (u16*)(ws + OFF_FCB);
    float* Dd    = (float*)(ws + OFF_DD);
    u16*   scb   = (u16*)(ws + OFF_SCB);

    k_prep_a  <<<GP_LN + GP_WIN + GP_WOUT, 256, 0, stream>>>
              (x, ln_g, ln_b, u_bf, W_in, winb, W_out, woutb);
    k_gemm_bt <<<dim3(NPAD / 128, BL / 128), 256, 0, stream>>>(u_bf, winb, BL, NPAD, DM, 1, zx, NPAD, nullptr, nullptr);
    k_prep_b  <<<GP_FCD + GP_DZ, 256, 0, stream>>>(fc_D_w, fcb, Dv, Dd);
    k_conv    <<<dim3(CONV_DIM / 64, L_ / 256, B_), 256, 0, stream>>>(zx, conv_w, conv_b, xs, BCb);
    k_dproj   <<<dim3(BL / 32, 8), 256, 0, stream>>>(xs, fcb, Dd);
    k_chunk   <<<4096, 256, 0, stream>>>(xs, BCb, zx, dt_bias, A_log, y0b, y1b, wo2, dec, scb);
    k_hscan   <<<1024, 256, 0, stream>>>(dec, scb);
    k_inter   <<<4096, 256, 0, stream>>>(BCb, wo2, scb, y0b, y1b);
    k_gate    <<<BL, 256, 0, stream>>>(xs, zx, y0b, y1b, Dd, norm_w, ynb);
    k_gemm_bt <<<dim3(DM / 128, BL / 128), 256, 0, stream>>>(ynb, woutb, BL, DM, DIN, 0, nullptr, DM, (float*)d_out, x);
}